// Round 14
// baseline (2759.860 us; speedup 1.0000x reference)
//
#include <hip/hip_runtime.h>
#include <hip/hip_bf16.h>

typedef __bf16 bf16_t;
typedef __bf16 bf16x8 __attribute__((ext_vector_type(8)));
typedef __bf16 bf16x4 __attribute__((ext_vector_type(4)));
typedef float f32x4 __attribute__((ext_vector_type(4)));
typedef unsigned int u32x4 __attribute__((ext_vector_type(4)));
typedef unsigned int u32x2 __attribute__((ext_vector_type(2)));

#define DEVI static __device__ __forceinline__

DEVI f32x4 mfma16(bf16x8 a, bf16x8 b, f32x4 c) {
  return __builtin_amdgcn_mfma_f32_16x16x32_bf16(a, b, c, 0, 0, 0);
}

DEVI float sigf(float x) { return 1.f / (1.f + __expf(-x)); }
DEVI float tanh_fast(float x) { return 2.f / (1.f + __expf(-2.f * x)) - 1.f; }

// ---------------------------------------------------------------------------
// Weight pre-swizzles, one launch (unchanged).
// Wsw[kc][nt][lane][j] = W[kc*32+(l>>4)*8+j][nt*16+(l&15)]  (m89 mapping).
// ---------------------------------------------------------------------------
DEVI void prep_one(const float* __restrict__ src, bf16_t* __restrict__ dst,
                   int K, int N, int gid) {
  int l = gid & 63;
  int fi = gid >> 6;
  int NT = N >> 4;
  int nt = fi % NT;
  int kc = fi / NT;
  int row0 = kc * 32 + (l >> 4) * 8;
  int col = nt * 16 + (l & 15);
  bf16x8 v;
#pragma unroll
  for (int j = 0; j < 8; ++j) v[j] = (bf16_t)src[(size_t)(row0 + j) * N + col];
  *(bf16x8*)(dst + (size_t)gid * 8) = v;
}

__global__ __launch_bounds__(256) void k_prep_all(
    const float* s0, bf16_t* d0, const float* s1, bf16_t* d1,
    const float* s2, bf16_t* d2, const float* s3, bf16_t* d3,
    const float* s4, bf16_t* d4, const float* s5, bf16_t* d5,
    const float* s6, bf16_t* d6, const float* s7, bf16_t* d7,
    const float* s8, bf16_t* d8, const float* s9, bf16_t* d9) {
  int b = blockIdx.x;
  if (b < 1024)       prep_one(s0, d0, 1024, 2048, (b - 0)    * 256 + threadIdx.x);
  else if (b < 2048)  prep_one(s1, d1, 1024, 2048, (b - 1024) * 256 + threadIdx.x);
  else if (b < 2560)  prep_one(s2, d2, 512, 2048,  (b - 2048) * 256 + threadIdx.x);
  else if (b < 3072)  prep_one(s3, d3, 512, 2048,  (b - 2560) * 256 + threadIdx.x);
  else if (b < 3584)  prep_one(s4, d4, 512, 2048,  (b - 3072) * 256 + threadIdx.x);
  else if (b < 4096)  prep_one(s5, d5, 512, 2048,  (b - 3584) * 256 + threadIdx.x);
  else if (b < 4608)  prep_one(s6, d6, 512, 2048,  (b - 4096) * 256 + threadIdx.x);
  else if (b < 5120)  prep_one(s7, d7, 512, 2048,  (b - 4608) * 256 + threadIdx.x);
  else if (b < 5632)  prep_one(s8, d8, 2048, 512,  (b - 5120) * 256 + threadIdx.x);
  else                prep_one(s9, d9, 2048, 512,  (b - 5632) * 256 + threadIdx.x);
}

// ---------------------------------------------------------------------------
// fp32 -> bf16 streaming convert (vectorized, grid-stride).
// ---------------------------------------------------------------------------
__global__ __launch_bounds__(256) void k_cvt(const float* __restrict__ src,
                                             bf16_t* __restrict__ dst, int n8) {
  int stride = gridDim.x * 256;
  for (int i = blockIdx.x * 256 + threadIdx.x; i < n8; i += stride) {
    const float4* p = (const float4*)(src + (size_t)i * 8);
    float4 u = p[0], v = p[1];
    bf16x8 o;
    o[0] = (bf16_t)u.x; o[1] = (bf16_t)u.y; o[2] = (bf16_t)u.z; o[3] = (bf16_t)u.w;
    o[4] = (bf16_t)v.x; o[5] = (bf16_t)v.y; o[6] = (bf16_t)v.z; o[7] = (bf16_t)v.w;
    *(bf16x8*)(dst + (size_t)i * 8) = o;
  }
}

// ---------------------------------------------------------------------------
// Fused producer/consumer kernel, v2.
// PRODUCERS (bids 0..127), N-SPLIT: item = (t, sd, nchunk of 16 chains);
//   computes ALL 2048 gate rows for those 16 chains. Each x element read
//   ONCE total (bf16); Wsw re-read comes from XCD L2 (resident slice).
//   Per wave: 32 m-tiles x 1 n-tile, acc[32] f32x4 = 128 VGPRs.
//   xg written with 8B agent-atomic stores (write-through IF$);
//   __syncthreads; leader adds xgf[sd*256+t] (8 adds complete a t).
// CONSUMERS (bids 128..255): r12 recurrence, unchanged (proven):
//   combined {xgf>=8, flg>=16} poll, batched sc1 loads, B-frag-major h.
// ---------------------------------------------------------------------------
__global__ __launch_bounds__(256, 1) void k_fused(
    const bf16_t* __restrict__ xbf_vid, const bf16_t* __restrict__ xbf_txt,
    const bf16_t* __restrict__ vWxf_sw, const bf16_t* __restrict__ vWxb_sw,
    const float* __restrict__ vbf, const float* __restrict__ vbb,
    const bf16_t* __restrict__ tWxf_sw, const bf16_t* __restrict__ tWxb_sw,
    const float* __restrict__ tbf, const float* __restrict__ tbb,
    const bf16_t* __restrict__ Wh_vid, const bf16_t* __restrict__ Wh_txt,
    bf16_t* __restrict__ xg_vid, bf16_t* __restrict__ xg_txt,
    bf16_t* __restrict__ hbuf, int* __restrict__ flags, int* __restrict__ xgf,
    bf16_t* __restrict__ feats) {
  int bid = blockIdx.x;
  int tid = threadIdx.x;
  int w = tid >> 6, l = tid & 63;
  int rl = l & 15, lh = l >> 4;

  if (bid < 128) {
    // ------------------------- producer role (n-split) -------------------------
    for (int i = bid; i < 5120; i += 128) {
      int t, sd, nch;
      if (i < 2048) {
        t = i >> 5; int r = i & 31; sd = r >> 3; nch = r & 7;
      } else {
        int j = i - 2048; t = 64 + (j >> 4); int r = j & 15; sd = r >> 3; nch = r & 7;
      }
      int species = sd >> 1, dirp = sd & 1;
      int T = species ? 64 : 256;
      int KD32 = species ? 16 : 32;
      const bf16_t* x = species ? xbf_txt : xbf_vid;
      const bf16_t* Wsw = species ? (dirp ? tWxb_sw : tWxf_sw)
                                  : (dirp ? vWxb_sw : vWxf_sw);
      const float* bias = species ? (dirp ? tbb : tbf) : (dirp ? vbb : vbf);
      bf16_t* xg = species ? (xg_txt + (size_t)dirp * 64 * (128 * 2048))
                           : (xg_vid + (size_t)dirp * 256 * (128 * 2048));
      int tt = dirp ? (T - 1 - t) : t;
      int KDIM = KD32 * 32;
      int chain = nch * 16 + rl;
      const bf16_t* xrow = x + ((size_t)chain * T + tt) * KDIM + lh * 8;

      f32x4 acc[32];
#pragma unroll
      for (int mi = 0; mi < 32; ++mi) acc[mi] = f32x4{0.f, 0.f, 0.f, 0.f};

#pragma unroll 1
      for (int kc = 0; kc < KD32; ++kc) {
        bf16x8 xb = *(const bf16x8*)(xrow + kc * 32);
        const bf16_t* wbase = Wsw + ((size_t)(kc * 128 + w * 32) * 64 + l) * 8;
#pragma unroll
        for (int mb = 0; mb < 4; ++mb) {
          bf16x8 aw[8];
#pragma unroll
          for (int u = 0; u < 8; ++u)
            aw[u] = *(const bf16x8*)(wbase + (size_t)(mb * 8 + u) * 512);
#pragma unroll
          for (int u = 0; u < 8; ++u)
            acc[mb * 8 + u] = mfma16(aw[u], xb, acc[mb * 8 + u]);
        }
      }

#pragma unroll
      for (int mi = 0; mi < 32; ++mi) {
        int m = w * 32 + mi;
        bf16x4 ov;
#pragma unroll
        for (int r = 0; r < 4; ++r)
          ov[r] = (bf16_t)(acc[mi][r] + bias[m * 16 + lh * 4 + r]);
        __hip_atomic_store(
            (unsigned long long*)(xg + (((size_t)t * 128 + m) * 8 + nch) * 256 + l * 4),
            __builtin_bit_cast(unsigned long long, ov),
            __ATOMIC_RELAXED, __HIP_MEMORY_SCOPE_AGENT);
      }
      __syncthreads();  // drain all waves' stores
      if (tid == 0)
        __hip_atomic_fetch_add(xgf + sd * 256 + t, 1, __ATOMIC_RELAXED,
                               __HIP_MEMORY_SCOPE_AGENT);
    }
    return;
  }

  // ------------------------- recurrence role (r12, proven) -------------------------
  int rb = bid - 128;
  int g = rb >> 4;             // group 0..7
  int wgi = rb & 15;           // WG within group
  int species = g >> 2, dir = (g >> 1) & 1, half = g & 1;
  int slot = wgi * 4 + w;      // 0..63
  int jt = slot >> 1;          // hidden-col tile 0..31
  int pp = slot & 1;           // chain-tile pair within the half
  int jb = jt * 16 + lh * 4;   // thread's hidden-col base

  int NT = species ? 64 : 256;
  const bf16_t* xg = (species ? xg_txt : xg_vid) + (size_t)dir * NT * (128 * 2048);
  const bf16_t* Wh = (species ? Wh_txt : Wh_vid) + (size_t)dir * (512 * 2048);
  bf16_t* hb = hbuf + (size_t)g * 2 * 32768;  // [parity][kc=16][ct=4][64][8]
  int* flg = flags + g * 256;
  const int* xfl0 = xgf + (species * 2 + dir) * 256;
  int colbase = species * 1024 + dir * 512;

  // Register-resident A-frags of Wh^T: gate m-tile = gg*32 + jt.
  bf16x8 Bw[16][4];
#pragma unroll
  for (int kc = 0; kc < 16; ++kc)
#pragma unroll
    for (int gg = 0; gg < 4; ++gg)
      Bw[kc][gg] = *(const bf16x8*)(Wh + ((size_t)(kc * 128 + gg * 32 + jt) * 64 + l) * 8);

  // h-store address components (B-fragment-major layout).
  int kc_w = jt >> 1;
  int l_w = ((jt & 1) * 2 + (lh >> 1)) * 16 + rl;
  int e_w = (lh & 1) * 4;

  float c[2][4];
#pragma unroll
  for (int nn = 0; nn < 2; ++nn)
#pragma unroll
    for (int r = 0; r < 4; ++r) c[nn][r] = 0.f;

  for (int s = 0; s < NT; ++s) {
    // Combined poll: xg[s] produced (>=8) AND group finished step s-1 (>=16).
    {
      const int* xfl = xfl0 + s;
      const int* fl = flg + (s > 0 ? s - 1 : 0);
      for (;;) {
        int a = __hip_atomic_load(xfl, __ATOMIC_RELAXED, __HIP_MEMORY_SCOPE_AGENT);
        int b = (s > 0)
                    ? __hip_atomic_load(fl, __ATOMIC_RELAXED, __HIP_MEMORY_SCOPE_AGENT)
                    : 16;
        if (a >= 8 && b >= 16) break;
        __builtin_amdgcn_s_sleep(1);
      }
      asm volatile("" ::: "memory");  // keep loads below the poll
    }

    // Batch-issue xg (8B) and h (16B) coherent loads; one waitcnt.
    u32x2 xr[4][2];
#pragma unroll
    for (int gg = 0; gg < 4; ++gg)
#pragma unroll
      for (int nn = 0; nn < 2; ++nn) {
        const bf16_t* xp =
            xg + (((size_t)s * 128 + gg * 32 + jt) * 8 + half * 4 + pp * 2 + nn) * 256 +
            l * 4;
        asm volatile("global_load_dwordx2 %0, %1, off sc1"
                     : "=v"(xr[gg][nn]) : "v"(xp) : "memory");
      }
    u32x4 hf[2][16];
    if (s > 0) {
      const bf16_t* hcur = hb + (size_t)(s & 1) * 32768;
#pragma unroll
      for (int nn = 0; nn < 2; ++nn) {
        int ct = pp * 2 + nn;
#pragma unroll
        for (int kc = 0; kc < 16; ++kc) {
          const bf16_t* hp = hcur + ((size_t)(kc * 4 + ct) * 64 + l) * 8;
          asm volatile("global_load_dwordx4 %0, %1, off sc1"
                       : "=v"(hf[nn][kc]) : "v"(hp) : "memory");
        }
      }
    }
    asm volatile("s_waitcnt vmcnt(0)" ::: "memory");
    __builtin_amdgcn_sched_barrier(0);

    f32x4 acc[4][2];
#pragma unroll
    for (int gg = 0; gg < 4; ++gg)
#pragma unroll
      for (int nn = 0; nn < 2; ++nn) {
        bf16x4 xv = __builtin_bit_cast(bf16x4, xr[gg][nn]);
        acc[gg][nn] = f32x4{(float)xv[0], (float)xv[1], (float)xv[2], (float)xv[3]};
      }

    if (s > 0) {
#pragma unroll
      for (int kc = 0; kc < 16; ++kc)
#pragma unroll
        for (int gg = 0; gg < 4; ++gg)
#pragma unroll
          for (int nn = 0; nn < 2; ++nn)
            acc[gg][nn] = mfma16(Bw[kc][gg], __builtin_bit_cast(bf16x8, hf[nn][kc]),
                                 acc[gg][nn]);
    }

    bf16_t* hnext = hb + (size_t)((s + 1) & 1) * 32768;
#pragma unroll
    for (int nn = 0; nn < 2; ++nn) {
      int ct = pp * 2 + nn;
      int chain = ct * 16 + rl;
      bf16x4 hv;
#pragma unroll
      for (int r = 0; r < 4; ++r) {
        float iv = acc[0][nn][r], fv = acc[1][nn][r];
        float gv = acc[2][nn][r], ov = acc[3][nn][r];
        float cn = sigf(fv) * c[nn][r] + sigf(iv) * tanh_fast(gv);
        c[nn][r] = cn;
        hv[r] = (bf16_t)(sigf(ov) * tanh_fast(cn));
      }
      __hip_atomic_store(
          (unsigned long long*)(hnext + ((size_t)(kc_w * 4 + ct) * 64 + l_w) * 8 + e_w),
          __builtin_bit_cast(unsigned long long, hv),
          __ATOMIC_RELAXED, __HIP_MEMORY_SCOPE_AGENT);
      if (s == NT - 1)
        *(bf16x4*)(feats + (size_t)(half * 64 + chain) * 2048 + colbase + jb) = hv;
    }

    __syncthreads();  // drains all 4 waves' vmcnt -> WG's h-stores visible
    if (tid == 0)
      __hip_atomic_fetch_add(flg + s, 1, __ATOMIC_RELAXED, __HIP_MEMORY_SCOPE_AGENT);
  }
}

// ---------------------------------------------------------------------------
// h1[mlp] = relu(feats @ W1[mlp] + b1[mlp]) : [128,2048]x[2048,512]
// ---------------------------------------------------------------------------
__global__ __launch_bounds__(256) void k_mlp(const bf16_t* __restrict__ feats,
                                             const bf16_t* __restrict__ W1sw,
                                             const float* __restrict__ sqb1,
                                             const float* __restrict__ rqb1,
                                             float* __restrict__ h1) {
  int mlp = blockIdx.x >> 3, chunk = blockIdx.x & 7;
  const bf16_t* Wsw = W1sw + (size_t)mlp * (2048 * 512);
  const float* b1 = mlp ? rqb1 : sqb1;
  int tid = threadIdx.x;
  int l = tid & 63, w = tid >> 6;
  int rl = l & 15, kl = (l >> 4) * 8;
  f32x4 acc[2][4];
#pragma unroll
  for (int mt = 0; mt < 2; ++mt)
#pragma unroll
    for (int nt = 0; nt < 4; ++nt) acc[mt][nt] = f32x4{0.f, 0.f, 0.f, 0.f};

  for (int kc = 0; kc < 64; ++kc) {
    bf16x8 a[2];
#pragma unroll
    for (int mt = 0; mt < 2; ++mt) {
      int row = w * 32 + mt * 16 + rl;
      a[mt] = *(const bf16x8*)(feats + (size_t)row * 2048 + kc * 32 + kl);
    }
#pragma unroll
    for (int nt = 0; nt < 4; ++nt) {
      int nt_g = chunk * 4 + nt;
      bf16x8 b = *(const bf16x8*)(Wsw + ((size_t)(kc * 32 + nt_g) * 64 + l) * 8);
#pragma unroll
      for (int mt = 0; mt < 2; ++mt) acc[mt][nt] = mfma16(a[mt], b, acc[mt][nt]);
    }
  }

#pragma unroll
  for (int mt = 0; mt < 2; ++mt)
#pragma unroll
    for (int nt = 0; nt < 4; ++nt) {
      int col = (chunk * 4 + nt) * 16 + rl;
      float bv = b1[col];
#pragma unroll
      for (int r = 0; r < 4; ++r) {
        int row = w * 32 + mt * 16 + (l >> 4) * 4 + r;
        float v = acc[mt][nt][r] + bv;
        h1[(size_t)mlp * (128 * 512) + (size_t)row * 512 + col] = v > 0.f ? v : 0.f;
      }
    }
}

// ---------------------------------------------------------------------------
__global__ __launch_bounds__(256) void k_final(const float* __restrict__ h1,
                                               const float* __restrict__ sqW2,
                                               const float* __restrict__ sqb2,
                                               const float* __restrict__ rqW2,
                                               const float* __restrict__ rqb2,
                                               const int* __restrict__ labels,
                                               float* __restrict__ out) {
  __shared__ float sc[128][2];
  int tid = threadIdx.x;
  int row = tid >> 1, m = tid & 1;
  const float* hp = h1 + ((size_t)m * 128 + row) * 512;
  const float* w2 = m ? rqW2 : sqW2;
  float s = m ? *rqb2 : *sqb2;
  for (int k = 0; k < 512; ++k) s += hp[k] * w2[k];
  sc[row][m] = s;
  __syncthreads();
  if (tid < 16) {
    float acc = 0.f;
    for (int i = 0; i < 8; ++i) {
      int r = tid * 8 + i;
      acc += (labels[r] <= 3) ? sc[r][0] : sc[r][1];
    }
    acc *= (1.f / 8.f);
    out[tid] = 1.f / (1.f + __expf(-acc));
  }
}

// ---------------------------------------------------------------------------
extern "C" void kernel_launch(void* const* d_in, const int* in_sizes, int n_in,
                              void* d_out, int out_size, void* d_ws, size_t ws_size,
                              hipStream_t stream) {
  const float* vid  = (const float*)d_in[0];
  const float* txt  = (const float*)d_in[1];
  const int* labels = (const int*)d_in[2];
  const float* vWxf = (const float*)d_in[3];
  const float* vWhf = (const float*)d_in[4];
  const float* vbf  = (const float*)d_in[5];
  const float* vWxb = (const float*)d_in[6];
  const float* vWhb = (const float*)d_in[7];
  const float* vbb  = (const float*)d_in[8];
  const float* tWxf = (const float*)d_in[9];
  const float* tWhf = (const float*)d_in[10];
  const float* tbf  = (const float*)d_in[11];
  const float* tWxb = (const float*)d_in[12];
  const float* tWhb = (const float*)d_in[13];
  const float* tbb  = (const float*)d_in[14];
  const float* sqW1 = (const float*)d_in[15];
  const float* sqb1 = (const float*)d_in[16];
  const float* sqW2 = (const float*)d_in[17];
  const float* sqb2 = (const float*)d_in[18];
  const float* rqW1 = (const float*)d_in[19];
  const float* rqb1 = (const float*)d_in[20];
  const float* rqW2 = (const float*)d_in[21];
  const float* rqb2 = (const float*)d_in[22];

  char* p = (char*)d_ws;
  auto alloc = [&](size_t bytes) {
    char* r = p;
    p += (bytes + 255) & ~(size_t)255;
    return r;
  };
  bf16_t* vWxf_sw = (bf16_t*)alloc((size_t)1024 * 2048 * 2);
  bf16_t* vWxb_sw = (bf16_t*)alloc((size_t)1024 * 2048 * 2);
  bf16_t* vWh_sw  = (bf16_t*)alloc((size_t)2 * 512 * 2048 * 2);  // [dir]
  bf16_t* tWxf_sw = (bf16_t*)alloc((size_t)512 * 2048 * 2);
  bf16_t* tWxb_sw = (bf16_t*)alloc((size_t)512 * 2048 * 2);
  bf16_t* tWh_sw  = (bf16_t*)alloc((size_t)2 * 512 * 2048 * 2);  // [dir]
  bf16_t* W1_sw   = (bf16_t*)alloc((size_t)2 * 2048 * 512 * 2);  // [mlp]
  bf16_t* xg_vid  = (bf16_t*)alloc((size_t)2 * 256 * 128 * 2048 * 2);
  bf16_t* xg_txt  = (bf16_t*)alloc((size_t)2 * 64 * 128 * 2048 * 2);
  bf16_t* xbf_vid = (bf16_t*)alloc((size_t)128 * 256 * 1024 * 2);
  bf16_t* xbf_txt = (bf16_t*)alloc((size_t)128 * 64 * 512 * 2);
  bf16_t* hbuf    = (bf16_t*)alloc((size_t)8 * 2 * 32768 * 2);   // [grp][parity]
  int*    flags   = (int*)alloc((size_t)8 * 256 * 4);            // h flags
  int*    xgf     = (int*)alloc((size_t)4 * 256 * 4);            // xg flags
  bf16_t* feats   = (bf16_t*)alloc((size_t)128 * 2048 * 2);
  float*  h1      = (float*)alloc((size_t)2 * 128 * 512 * 4);
  (void)ws_size; (void)in_sizes; (void)n_in; (void)out_size;

  k_prep_all<<<6144, 256, 0, stream>>>(
      vWxf, vWxf_sw, vWxb, vWxb_sw, vWhf, vWh_sw,
      vWhb, vWh_sw + (size_t)512 * 2048, tWxf, tWxf_sw, tWxb, tWxb_sw,
      tWhf, tWh_sw, tWhb, tWh_sw + (size_t)512 * 2048,
      sqW1, W1_sw, rqW1, W1_sw + (size_t)2048 * 512);

  k_cvt<<<2048, 256, 0, stream>>>(vid, xbf_vid, 128 * 256 * 1024 / 8);
  k_cvt<<<512, 256, 0, stream>>>(txt, xbf_txt, 128 * 64 * 512 / 8);

  // flags (8KB) and xgf (4KB) are contiguous in the workspace
  hipMemsetAsync(flags, 0, (size_t)8 * 256 * 4 + (size_t)4 * 256 * 4, stream);

  k_fused<<<256, 256, 0, stream>>>(
      xbf_vid, xbf_txt, vWxf_sw, vWxb_sw, vbf, vbb, tWxf_sw, tWxb_sw, tbf, tbb,
      vWh_sw, tWh_sw, xg_vid, xg_txt, hbuf, flags, xgf, feats);

  k_mlp<<<16, 256, 0, stream>>>(feats, W1_sw, sqb1, rqb1, h1);
  k_final<<<1, 256, 0, stream>>>(h1, sqW2, sqb2, rqW2, rqb2, labels, (float*)d_out);
}

// Round 15
// 2007.164 us; speedup vs baseline: 1.3750x; 1.3750x over previous
//
#include <hip/hip_runtime.h>
#include <hip/hip_bf16.h>

typedef __bf16 bf16_t;
typedef __bf16 bf16x8 __attribute__((ext_vector_type(8)));
typedef __bf16 bf16x4 __attribute__((ext_vector_type(4)));
typedef float f32x4 __attribute__((ext_vector_type(4)));
typedef unsigned int u32x4 __attribute__((ext_vector_type(4)));
typedef unsigned int u32x2 __attribute__((ext_vector_type(2)));

#define DEVI static __device__ __forceinline__

DEVI f32x4 mfma16(bf16x8 a, bf16x8 b, f32x4 c) {
  return __builtin_amdgcn_mfma_f32_16x16x32_bf16(a, b, c, 0, 0, 0);
}

DEVI float sigf(float x) { return 1.f / (1.f + __expf(-x)); }
DEVI float tanh_fast(float x) { return 2.f / (1.f + __expf(-2.f * x)) - 1.f; }

// ---------------------------------------------------------------------------
// Combined pre-pass: weight swizzles (blocks 0..6143) + f32->bf16 input
// converts (blocks 6144..8447). One launch instead of three.
// Wsw[kc][nt][lane][j] = W[kc*32+(l>>4)*8+j][nt*16+(l&15)]  (m89 mapping).
// ---------------------------------------------------------------------------
DEVI void prep_one(const float* __restrict__ src, bf16_t* __restrict__ dst,
                   int K, int N, int gid) {
  int l = gid & 63;
  int fi = gid >> 6;
  int NT = N >> 4;
  int nt = fi % NT;
  int kc = fi / NT;
  int row0 = kc * 32 + (l >> 4) * 8;
  int col = nt * 16 + (l & 15);
  bf16x8 v;
#pragma unroll
  for (int j = 0; j < 8; ++j) v[j] = (bf16_t)src[(size_t)(row0 + j) * N + col];
  *(bf16x8*)(dst + (size_t)gid * 8) = v;
}

DEVI void cvt_range(const float* __restrict__ src, bf16_t* __restrict__ dst,
                    int n8, int tid0, int nthreads) {
  for (int i = tid0; i < n8; i += nthreads) {
    const float4* p = (const float4*)(src + (size_t)i * 8);
    float4 u = p[0], v = p[1];
    bf16x8 o;
    o[0] = (bf16_t)u.x; o[1] = (bf16_t)u.y; o[2] = (bf16_t)u.z; o[3] = (bf16_t)u.w;
    o[4] = (bf16_t)v.x; o[5] = (bf16_t)v.y; o[6] = (bf16_t)v.z; o[7] = (bf16_t)v.w;
    *(bf16x8*)(dst + (size_t)i * 8) = o;
  }
}

__global__ __launch_bounds__(256) void k_pre(
    const float* s0, bf16_t* d0, const float* s1, bf16_t* d1,
    const float* s2, bf16_t* d2, const float* s3, bf16_t* d3,
    const float* s4, bf16_t* d4, const float* s5, bf16_t* d5,
    const float* s6, bf16_t* d6, const float* s7, bf16_t* d7,
    const float* s8, bf16_t* d8, const float* s9, bf16_t* d9,
    const float* vid, bf16_t* xbf_vid, const float* txt, bf16_t* xbf_txt) {
  int b = blockIdx.x;
  if (b < 1024)       prep_one(s0, d0, 1024, 2048, (b - 0)    * 256 + threadIdx.x);
  else if (b < 2048)  prep_one(s1, d1, 1024, 2048, (b - 1024) * 256 + threadIdx.x);
  else if (b < 2560)  prep_one(s2, d2, 512, 2048,  (b - 2048) * 256 + threadIdx.x);
  else if (b < 3072)  prep_one(s3, d3, 512, 2048,  (b - 2560) * 256 + threadIdx.x);
  else if (b < 3584)  prep_one(s4, d4, 512, 2048,  (b - 3072) * 256 + threadIdx.x);
  else if (b < 4096)  prep_one(s5, d5, 512, 2048,  (b - 3584) * 256 + threadIdx.x);
  else if (b < 4608)  prep_one(s6, d6, 512, 2048,  (b - 4096) * 256 + threadIdx.x);
  else if (b < 5120)  prep_one(s7, d7, 512, 2048,  (b - 4608) * 256 + threadIdx.x);
  else if (b < 5632)  prep_one(s8, d8, 2048, 512,  (b - 5120) * 256 + threadIdx.x);
  else if (b < 6144)  prep_one(s9, d9, 2048, 512,  (b - 5632) * 256 + threadIdx.x);
  else if (b < 8192)
    cvt_range(vid, xbf_vid, 128 * 256 * 1024 / 8,
              (b - 6144) * 256 + threadIdx.x, 2048 * 256);
  else
    cvt_range(txt, xbf_txt, 128 * 64 * 512 / 8,
              (b - 8192) * 256 + threadIdx.x, 256 * 256);
}

// ---------------------------------------------------------------------------
// All four input projections in ONE launch (bf16 x): xg^T = Wx^T @ x^T + b.
// Blocks 0..2047 vid dir0, 2048..4095 vid dir1, 4096..4607 txt dir0,
// 4608..5119 txt dir1. Inner code identical to r12's k_proj.
// Output xg fragment-major: xg[((t*128 + m)*8 + n)*256 + l*4 + r] (bf16).
// ---------------------------------------------------------------------------
__global__ __launch_bounds__(256) void k_proj_all(
    const bf16_t* __restrict__ xbf_vid, const bf16_t* __restrict__ xbf_txt,
    const bf16_t* __restrict__ vWxf_sw, const bf16_t* __restrict__ vWxb_sw,
    const float* __restrict__ vbf, const float* __restrict__ vbb,
    const bf16_t* __restrict__ tWxf_sw, const bf16_t* __restrict__ tWxb_sw,
    const float* __restrict__ tbf, const float* __restrict__ tbb,
    bf16_t* __restrict__ xg_vid, bf16_t* __restrict__ xg_txt) {
  int b = blockIdx.x;
  const bf16_t* x;
  const bf16_t* Wsw;
  const float* bias;
  bf16_t* xg;
  int T, KD32, bb;
  if (b < 4096) {
    int dir = b >> 11;
    bb = b & 2047;
    T = 256; KD32 = 32;
    x = xbf_vid;
    Wsw = dir ? vWxb_sw : vWxf_sw;
    bias = dir ? vbb : vbf;
    xg = xg_vid + (size_t)dir * 256 * (128 * 2048);
    if (dir) bb = bb;  // t mapping below
    // t index is bb>>3; dir handled via tt below
    int chunk = bb & 7;
    int t = bb >> 3;
    int tt = dir ? (T - 1 - t) : t;
    int tid = threadIdx.x;
    int l = tid & 63, w = tid >> 6;
    int rl = l & 15, lh = l >> 4;
    int m0 = chunk * 16 + w * 4;
    f32x4 acc[4][8];
#pragma unroll
    for (int mi = 0; mi < 4; ++mi)
#pragma unroll
      for (int n = 0; n < 8; ++n) acc[mi][n] = f32x4{0.f, 0.f, 0.f, 0.f};
    for (int kc = 0; kc < 32; ++kc) {
      bf16x8 aw[4];
#pragma unroll
      for (int mi = 0; mi < 4; ++mi)
        aw[mi] = *(const bf16x8*)(Wsw + ((size_t)(kc * 128 + m0 + mi) * 64 + l) * 8);
      bf16x8 xb[8];
#pragma unroll
      for (int n = 0; n < 8; ++n) {
        int chain = n * 16 + rl;
        xb[n] = *(const bf16x8*)(x + ((size_t)chain * T + tt) * 1024 + kc * 32 + lh * 8);
      }
#pragma unroll
      for (int mi = 0; mi < 4; ++mi)
#pragma unroll
        for (int n = 0; n < 8; ++n) acc[mi][n] = mfma16(aw[mi], xb[n], acc[mi][n]);
    }
#pragma unroll
    for (int mi = 0; mi < 4; ++mi) {
      int m = m0 + mi;
      float bv[4];
#pragma unroll
      for (int r = 0; r < 4; ++r) bv[r] = bias[m * 16 + lh * 4 + r];
#pragma unroll
      for (int n = 0; n < 8; ++n) {
        bf16x4 ov;
#pragma unroll
        for (int r = 0; r < 4; ++r) ov[r] = (bf16_t)(acc[mi][n][r] + bv[r]);
        *(bf16x4*)(xg + (((size_t)t * 128 + m) * 8 + n) * 256 + l * 4) = ov;
      }
    }
  } else {
    b -= 4096;
    int dir = b >> 9;
    bb = b & 511;
    T = 64; KD32 = 16;
    x = xbf_txt;
    Wsw = dir ? tWxb_sw : tWxf_sw;
    bias = dir ? tbb : tbf;
    xg = xg_txt + (size_t)dir * 64 * (128 * 2048);
    int chunk = bb & 7;
    int t = bb >> 3;
    int tt = dir ? (T - 1 - t) : t;
    int tid = threadIdx.x;
    int l = tid & 63, w = tid >> 6;
    int rl = l & 15, lh = l >> 4;
    int m0 = chunk * 16 + w * 4;
    f32x4 acc[4][8];
#pragma unroll
    for (int mi = 0; mi < 4; ++mi)
#pragma unroll
      for (int n = 0; n < 8; ++n) acc[mi][n] = f32x4{0.f, 0.f, 0.f, 0.f};
    for (int kc = 0; kc < 16; ++kc) {
      bf16x8 aw[4];
#pragma unroll
      for (int mi = 0; mi < 4; ++mi)
        aw[mi] = *(const bf16x8*)(Wsw + ((size_t)(kc * 128 + m0 + mi) * 64 + l) * 8);
      bf16x8 xb[8];
#pragma unroll
      for (int n = 0; n < 8; ++n) {
        int chain = n * 16 + rl;
        xb[n] = *(const bf16x8*)(x + ((size_t)chain * T + tt) * 512 + kc * 32 + lh * 8);
      }
#pragma unroll
      for (int mi = 0; mi < 4; ++mi)
#pragma unroll
        for (int n = 0; n < 8; ++n) acc[mi][n] = mfma16(aw[mi], xb[n], acc[mi][n]);
    }
#pragma unroll
    for (int mi = 0; mi < 4; ++mi) {
      int m = m0 + mi;
      float bv[4];
#pragma unroll
      for (int r = 0; r < 4; ++r) bv[r] = bias[m * 16 + lh * 4 + r];
#pragma unroll
      for (int n = 0; n < 8; ++n) {
        bf16x4 ov;
#pragma unroll
        for (int r = 0; r < 4; ++r) ov[r] = (bf16_t)(acc[mi][n][r] + bv[r]);
        *(bf16x4*)(xg + (((size_t)t * 128 + m) * 8 + n) * 256 + l * 4) = ov;
      }
    }
  }
}

// ---------------------------------------------------------------------------
// Persistent recurrence — byte-identical to r12 (proven 1277 us):
// B-fragment-major h, batched 16B sc1 loads, per-step group flags.
// ---------------------------------------------------------------------------
__global__ __launch_bounds__(256, 1) void k_rnn(
    const bf16_t* __restrict__ xg_vid, const bf16_t* __restrict__ xg_txt,
    const bf16_t* __restrict__ Wh_vid, const bf16_t* __restrict__ Wh_txt,
    bf16_t* __restrict__ hbuf, int* __restrict__ flags,
    bf16_t* __restrict__ feats) {
  int bid = blockIdx.x;
  int g = bid >> 4;            // group 0..7
  int wgi = bid & 15;          // WG within group
  int species = g >> 2, dir = (g >> 1) & 1, half = g & 1;
  int tid = threadIdx.x;
  int w = tid >> 6, l = tid & 63;
  int slot = wgi * 4 + w;      // 0..63
  int jt = slot >> 1;          // hidden-col tile 0..31
  int pp = slot & 1;           // chain-tile pair within the half
  int rl = l & 15, lh = l >> 4;
  int jb = jt * 16 + lh * 4;   // thread's hidden-col base

  int NT = species ? 64 : 256;
  const bf16_t* xg = (species ? xg_txt : xg_vid) + (size_t)dir * NT * (128 * 2048);
  const bf16_t* Wh = (species ? Wh_txt : Wh_vid) + (size_t)dir * (512 * 2048);
  bf16_t* hb = hbuf + (size_t)g * 2 * 32768;  // [parity][kc=16][ct=4][64][8]
  int* flg = flags + g * 256;
  int colbase = species * 1024 + dir * 512;

  bf16x8 Bw[16][4];
#pragma unroll
  for (int kc = 0; kc < 16; ++kc)
#pragma unroll
    for (int gg = 0; gg < 4; ++gg)
      Bw[kc][gg] = *(const bf16x8*)(Wh + ((size_t)(kc * 128 + gg * 32 + jt) * 64 + l) * 8);

  int kc_w = jt >> 1;
  int l_w = ((jt & 1) * 2 + (lh >> 1)) * 16 + rl;
  int e_w = (lh & 1) * 4;

  float c[2][4];
#pragma unroll
  for (int nn = 0; nn < 2; ++nn)
#pragma unroll
    for (int r = 0; r < 4; ++r) c[nn][r] = 0.f;

  for (int s = 0; s < NT; ++s) {
    bf16x4 xv[4][2];
#pragma unroll
    for (int gg = 0; gg < 4; ++gg)
#pragma unroll
      for (int nn = 0; nn < 2; ++nn)
        xv[gg][nn] = *(const bf16x4*)(
            xg + (((size_t)s * 128 + gg * 32 + jt) * 8 + half * 4 + pp * 2 + nn) * 256 +
            l * 4);

    f32x4 acc[4][2];
#pragma unroll
    for (int gg = 0; gg < 4; ++gg)
#pragma unroll
      for (int nn = 0; nn < 2; ++nn)
        acc[gg][nn] = f32x4{(float)xv[gg][nn][0], (float)xv[gg][nn][1],
                            (float)xv[gg][nn][2], (float)xv[gg][nn][3]};

    if (s > 0) {
      const int* fl = flg + (s - 1);
      while (__hip_atomic_load(fl, __ATOMIC_RELAXED, __HIP_MEMORY_SCOPE_AGENT) < 16)
        __builtin_amdgcn_s_sleep(1);
      asm volatile("" ::: "memory");

      const bf16_t* hcur = hb + (size_t)(s & 1) * 32768;
      u32x4 hf[2][16];
#pragma unroll
      for (int nn = 0; nn < 2; ++nn) {
        int ct = pp * 2 + nn;
#pragma unroll
        for (int kc = 0; kc < 16; ++kc) {
          const bf16_t* hp = hcur + ((size_t)(kc * 4 + ct) * 64 + l) * 8;
          asm volatile("global_load_dwordx4 %0, %1, off sc1"
                       : "=v"(hf[nn][kc]) : "v"(hp) : "memory");
        }
      }
      asm volatile("s_waitcnt vmcnt(0)" ::: "memory");
      __builtin_amdgcn_sched_barrier(0);
#pragma unroll
      for (int kc = 0; kc < 16; ++kc)
#pragma unroll
        for (int gg = 0; gg < 4; ++gg)
#pragma unroll
          for (int nn = 0; nn < 2; ++nn)
            acc[gg][nn] = mfma16(Bw[kc][gg], __builtin_bit_cast(bf16x8, hf[nn][kc]),
                                 acc[gg][nn]);
    }

    bf16_t* hnext = hb + (size_t)((s + 1) & 1) * 32768;
#pragma unroll
    for (int nn = 0; nn < 2; ++nn) {
      int ct = pp * 2 + nn;
      int chain = ct * 16 + rl;
      bf16x4 hv;
#pragma unroll
      for (int r = 0; r < 4; ++r) {
        float iv = acc[0][nn][r], fv = acc[1][nn][r];
        float gv = acc[2][nn][r], ov = acc[3][nn][r];
        float cn = sigf(fv) * c[nn][r] + sigf(iv) * tanh_fast(gv);
        c[nn][r] = cn;
        hv[r] = (bf16_t)(sigf(ov) * tanh_fast(cn));
      }
      __hip_atomic_store(
          (unsigned long long*)(hnext + ((size_t)(kc_w * 4 + ct) * 64 + l_w) * 8 + e_w),
          __builtin_bit_cast(unsigned long long, hv),
          __ATOMIC_RELAXED, __HIP_MEMORY_SCOPE_AGENT);
      if (s == NT - 1)
        *(bf16x4*)(feats + (size_t)(half * 64 + chain) * 2048 + colbase + jb) = hv;
    }

    __syncthreads();
    if (tid == 0)
      __hip_atomic_fetch_add(flg + s, 1, __ATOMIC_RELAXED, __HIP_MEMORY_SCOPE_AGENT);
  }
}

// ---------------------------------------------------------------------------
// h1[mlp] = relu(feats @ W1[mlp] + b1[mlp]) : [128,2048]x[2048,512]
// ---------------------------------------------------------------------------
__global__ __launch_bounds__(256) void k_mlp(const bf16_t* __restrict__ feats,
                                             const bf16_t* __restrict__ W1sw,
                                             const float* __restrict__ sqb1,
                                             const float* __restrict__ rqb1,
                                             float* __restrict__ h1) {
  int mlp = blockIdx.x >> 3, chunk = blockIdx.x & 7;
  const bf16_t* Wsw = W1sw + (size_t)mlp * (2048 * 512);
  const float* b1 = mlp ? rqb1 : sqb1;
  int tid = threadIdx.x;
  int l = tid & 63, w = tid >> 6;
  int rl = l & 15, kl = (l >> 4) * 8;
  f32x4 acc[2][4];
#pragma unroll
  for (int mt = 0; mt < 2; ++mt)
#pragma unroll
    for (int nt = 0; nt < 4; ++nt) acc[mt][nt] = f32x4{0.f, 0.f, 0.f, 0.f};

  for (int kc = 0; kc < 64; ++kc) {
    bf16x8 a[2];
#pragma unroll
    for (int mt = 0; mt < 2; ++mt) {
      int row = w * 32 + mt * 16 + rl;
      a[mt] = *(const bf16x8*)(feats + (size_t)row * 2048 + kc * 32 + kl);
    }
#pragma unroll
    for (int nt = 0; nt < 4; ++nt) {
      int nt_g = chunk * 4 + nt;
      bf16x8 b = *(const bf16x8*)(Wsw + ((size_t)(kc * 32 + nt_g) * 64 + l) * 8);
#pragma unroll
      for (int mt = 0; mt < 2; ++mt) acc[mt][nt] = mfma16(a[mt], b, acc[mt][nt]);
    }
  }

#pragma unroll
  for (int mt = 0; mt < 2; ++mt)
#pragma unroll
    for (int nt = 0; nt < 4; ++nt) {
      int col = (chunk * 4 + nt) * 16 + rl;
      float bv = b1[col];
#pragma unroll
      for (int r = 0; r < 4; ++r) {
        int row = w * 32 + mt * 16 + (l >> 4) * 4 + r;
        float v = acc[mt][nt][r] + bv;
        h1[(size_t)mlp * (128 * 512) + (size_t)row * 512 + col] = v > 0.f ? v : 0.f;
      }
    }
}

// ---------------------------------------------------------------------------
__global__ __launch_bounds__(256) void k_final(const float* __restrict__ h1,
                                               const float* __restrict__ sqW2,
                                               const float* __restrict__ sqb2,
                                               const float* __restrict__ rqW2,
                                               const float* __restrict__ rqb2,
                                               const int* __restrict__ labels,
                                               float* __restrict__ out) {
  __shared__ float sc[128][2];
  int tid = threadIdx.x;
  int row = tid >> 1, m = tid & 1;
  const float* hp = h1 + ((size_t)m * 128 + row) * 512;
  const float* w2 = m ? rqW2 : sqW2;
  float s = m ? *rqb2 : *sqb2;
  for (int k = 0; k < 512; ++k) s += hp[k] * w2[k];
  sc[row][m] = s;
  __syncthreads();
  if (tid < 16) {
    float acc = 0.f;
    for (int i = 0; i < 8; ++i) {
      int r = tid * 8 + i;
      acc += (labels[r] <= 3) ? sc[r][0] : sc[r][1];
    }
    acc *= (1.f / 8.f);
    out[tid] = 1.f / (1.f + __expf(-acc));
  }
}

// ---------------------------------------------------------------------------
extern "C" void kernel_launch(void* const* d_in, const int* in_sizes, int n_in,
                              void* d_out, int out_size, void* d_ws, size_t ws_size,
                              hipStream_t stream) {
  const float* vid  = (const float*)d_in[0];
  const float* txt  = (const float*)d_in[1];
  const int* labels = (const int*)d_in[2];
  const float* vWxf = (const float*)d_in[3];
  const float* vWhf = (const float*)d_in[4];
  const float* vbf  = (const float*)d_in[5];
  const float* vWxb = (const float*)d_in[6];
  const float* vWhb = (const float*)d_in[7];
  const float* vbb  = (const float*)d_in[8];
  const float* tWxf = (const float*)d_in[9];
  const float* tWhf = (const float*)d_in[10];
  const float* tbf  = (const float*)d_in[11];
  const float* tWxb = (const float*)d_in[12];
  const float* tWhb = (const float*)d_in[13];
  const float* tbb  = (const float*)d_in[14];
  const float* sqW1 = (const float*)d_in[15];
  const float* sqb1 = (const float*)d_in[16];
  const float* sqW2 = (const float*)d_in[17];
  const float* sqb2 = (const float*)d_in[18];
  const float* rqW1 = (const float*)d_in[19];
  const float* rqb1 = (const float*)d_in[20];
  const float* rqW2 = (const float*)d_in[21];
  const float* rqb2 = (const float*)d_in[22];

  char* p = (char*)d_ws;
  auto alloc = [&](size_t bytes) {
    char* r = p;
    p += (bytes + 255) & ~(size_t)255;
    return r;
  };
  bf16_t* vWxf_sw = (bf16_t*)alloc((size_t)1024 * 2048 * 2);
  bf16_t* vWxb_sw = (bf16_t*)alloc((size_t)1024 * 2048 * 2);
  bf16_t* vWh_sw  = (bf16_t*)alloc((size_t)2 * 512 * 2048 * 2);  // [dir]
  bf16_t* tWxf_sw = (bf16_t*)alloc((size_t)512 * 2048 * 2);
  bf16_t* tWxb_sw = (bf16_t*)alloc((size_t)512 * 2048 * 2);
  bf16_t* tWh_sw  = (bf16_t*)alloc((size_t)2 * 512 * 2048 * 2);  // [dir]
  bf16_t* W1_sw   = (bf16_t*)alloc((size_t)2 * 2048 * 512 * 2);  // [mlp]
  bf16_t* xg_vid  = (bf16_t*)alloc((size_t)2 * 256 * 128 * 2048 * 2);
  bf16_t* xg_txt  = (bf16_t*)alloc((size_t)2 * 64 * 128 * 2048 * 2);
  bf16_t* xbf_vid = (bf16_t*)alloc((size_t)128 * 256 * 1024 * 2);
  bf16_t* xbf_txt = (bf16_t*)alloc((size_t)128 * 64 * 512 * 2);
  bf16_t* hbuf    = (bf16_t*)alloc((size_t)8 * 2 * 32768 * 2);   // [grp][parity]
  int*    flags   = (int*)alloc((size_t)8 * 256 * 4);
  bf16_t* feats   = (bf16_t*)alloc((size_t)128 * 2048 * 2);
  float*  h1      = (float*)alloc((size_t)2 * 128 * 512 * 4);
  (void)ws_size; (void)in_sizes; (void)n_in; (void)out_size;

  k_pre<<<8448, 256, 0, stream>>>(
      vWxf, vWxf_sw, vWxb, vWxb_sw, vWhf, vWh_sw,
      vWhb, vWh_sw + (size_t)512 * 2048, tWxf, tWxf_sw, tWxb, tWxb_sw,
      tWhf, tWh_sw, tWhb, tWh_sw + (size_t)512 * 2048,
      sqW1, W1_sw, rqW1, W1_sw + (size_t)2048 * 512,
      vid, xbf_vid, txt, xbf_txt);

  hipMemsetAsync(flags, 0, (size_t)8 * 256 * 4, stream);

  k_proj_all<<<5120, 256, 0, stream>>>(
      xbf_vid, xbf_txt, vWxf_sw, vWxb_sw, vbf, vbb, tWxf_sw, tWxb_sw, tbf, tbb,
      xg_vid, xg_txt);

  k_rnn<<<128, 256, 0, stream>>>(xg_vid, xg_txt, vWh_sw, tWh_sw, hbuf, flags, feats);

  k_mlp<<<16, 256, 0, stream>>>(feats, W1_sw, sqb1, rqb1, h1);
  k_final<<<1, 256, 0, stream>>>(h1, sqW2, sqb2, rqW2, rqb2, labels, (float*)d_out);
}